// Round 1
// baseline (226.248 us; speedup 1.0000x reference)
//
#include <hip/hip_runtime.h>
#include <math.h>

#define NA 3
#define NM 32
#define NC 80
#define STRIDE_PX 8.0f
#define THRESH 0.05f
#define NB 16
#define NH 80
#define NW 80
#define NHW (NH * NW)                 // 6400
#define CH (NA * (5 + NC) + NA * NM)  // 351
#define BOXCH (NA * (5 + NC))         // 255
#define TOTAL (NB * NA * NHW)         // 307200
#define BLK 256
#define NBLK (TOTAL / BLK)            // 1200
#define ROWSZ (7 + NM)                // 39

// ---------------- pass 1: score everything, store decoded vals, per-block keep counts ----
__global__ __launch_bounds__(BLK) void pass1_kernel(
    const float* __restrict__ in, const float* __restrict__ anchors,
    float* __restrict__ vals, int* __restrict__ counts) {
  int g = blockIdx.x * BLK + threadIdx.x;
  int p = g % NHW;
  int a = (g / NHW) % NA;
  int b = g / (NA * NHW);

  const float* base = in + ((size_t)b * CH + (size_t)a * (5 + NC)) * NHW + p;

  float tx = base[0];
  float ty = base[(size_t)1 * NHW];
  float tw = base[(size_t)2 * NHW];
  float th = base[(size_t)3 * NHW];
  float tobj = base[(size_t)4 * NHW];

  // class logits in registers (single HBM pass)
  float cl[NC];
  float m = -INFINITY;
  int idx = 0;
#pragma unroll
  for (int j = 0; j < NC; ++j) {
    cl[j] = base[(size_t)(5 + j) * NHW];
    if (cl[j] > m) { m = cl[j]; idx = j; }  // strict > => first occurrence (jnp.argmax)
  }
  float s = 0.f;
#pragma unroll
  for (int j = 0; j < NC; ++j) s += expf(cl[j] - m);

  float cls_max = 1.0f / s;                 // exp(0)/sum
  float obj = 1.0f / (1.0f + expf(-tobj));
  float score = cls_max * obj;

  // anchors: max over all 6 entries for the exp clamp
  float amax = anchors[0];
#pragma unroll
  for (int j = 1; j < NA * 2; ++j) amax = fmaxf(amax, anchors[j]);
  float max_value = floorf(logf(1e35f / amax / STRIDE_PX));

  float aw = anchors[a * 2 + 0];
  float ah = anchors[a * 2 + 1];

  float xs = 1.0f / (1.0f + expf(-tx)) + (float)(p % NW);
  float ys = 1.0f / (1.0f + expf(-ty)) + (float)(p / NW);
  float w = expf(fminf(tw, max_value)) * aw;
  float h = expf(fminf(th, max_value)) * ah;

  float4 v0 = make_float4(xs, ys, w, h);
  float4 v1 = make_float4(score, (float)idx, 0.f, 0.f);
  float4* vp = (float4*)vals;
  vp[(size_t)g * 2 + 0] = v0;
  vp[(size_t)g * 2 + 1] = v1;

  // per-block keep count
  bool keep = score > THRESH;
  unsigned long long ball = __ballot(keep);
  __shared__ int wc[BLK / 64];
  int lane = threadIdx.x & 63;
  int wv = threadIdx.x >> 6;
  if (lane == 0) wc[wv] = __popcll(ball);
  __syncthreads();
  if (threadIdx.x == 0) {
    int t = 0;
#pragma unroll
    for (int w2 = 0; w2 < BLK / 64; ++w2) t += wc[w2];
    counts[blockIdx.x] = t;
  }
}

// ---------------- pass 2: exclusive scan of 1200 block counts (single block) -------------
__global__ __launch_bounds__(256) void scan_kernel(const int* __restrict__ counts,
                                                   int* __restrict__ offsets) {
  __shared__ int sh[2048];
  int t = threadIdx.x;
  for (int i = t; i < 2048; i += 256) sh[i] = (i < NBLK) ? counts[i] : 0;
  __syncthreads();
  for (int d = 1; d < 2048; d <<= 1) {
    int v[8];
#pragma unroll
    for (int k = 0; k < 8; ++k) {
      int i = t + k * 256;
      v[k] = (i >= d) ? sh[i - d] : 0;
    }
    __syncthreads();
#pragma unroll
    for (int k = 0; k < 8; ++k) sh[t + k * 256] += v[k];
    __syncthreads();
  }
  for (int i = t; i < NBLK; i += 256) offsets[i] = (i == 0) ? 0 : sh[i - 1];
}

// ---------------- pass 3: compact kept rows, gather mask coefficients -------------------
__global__ __launch_bounds__(BLK) void pass3_kernel(
    const float* __restrict__ in, const float* __restrict__ vals,
    const int* __restrict__ offsets, float* __restrict__ out, int out_size) {
  int g = blockIdx.x * BLK + threadIdx.x;
  int p = g % NHW;
  int a = (g / NHW) % NA;
  int b = g / (NA * NHW);

  const float4* vp = (const float4*)vals;
  float4 v0 = vp[(size_t)g * 2 + 0];
  float4 v1 = vp[(size_t)g * 2 + 1];
  float score = v1.x;
  bool keep = score > THRESH;

  unsigned long long ball = __ballot(keep);
  int lane = threadIdx.x & 63;
  int wv = threadIdx.x >> 6;
  int lower = __popcll(ball & ((1ull << lane) - 1ull));
  __shared__ int wc[BLK / 64];
  if (lane == 0) wc[wv] = __popcll(ball);
  __syncthreads();
  int pre = 0;
  for (int w2 = 0; w2 < wv; ++w2) pre += wc[w2];

  if (keep) {
    int row = offsets[blockIdx.x] + pre + lower;
    if ((size_t)(row + 1) * ROWSZ <= (size_t)out_size) {
      float* o = out + (size_t)row * ROWSZ;
      o[0] = (float)b;
      o[1] = v0.x * STRIDE_PX;
      o[2] = v0.y * STRIDE_PX;
      o[3] = v0.z * STRIDE_PX;
      o[4] = v0.w * STRIDE_PX;
      const float* mbase = in + ((size_t)b * CH + BOXCH + (size_t)a * NM) * NHW + p;
#pragma unroll
      for (int mm = 0; mm < NM; ++mm) o[5 + mm] = mbase[(size_t)mm * NHW];
      o[5 + NM] = score;       // 37
      o[6 + NM] = v1.y;        // 38: cls_idx
    }
  }
}

extern "C" void kernel_launch(void* const* d_in, const int* in_sizes, int n_in,
                              void* d_out, int out_size, void* d_ws, size_t ws_size,
                              hipStream_t stream) {
  const float* in = (const float*)d_in[0];
  const float* anchors = (const float*)d_in[1];

  float* vals = (float*)d_ws;                                   // TOTAL * 8 floats
  int* counts = (int*)((char*)d_ws + (size_t)TOTAL * 8 * 4);    // NBLK ints
  int* offsets = counts + NBLK;                                 // NBLK ints

  pass1_kernel<<<NBLK, BLK, 0, stream>>>(in, anchors, vals, counts);
  scan_kernel<<<1, 256, 0, stream>>>(counts, offsets);
  pass3_kernel<<<NBLK, BLK, 0, stream>>>(in, vals, offsets, (float*)d_out, out_size);
}